// Round 10
// baseline (323.497 us; speedup 1.0000x reference)
//
#include <hip/hip_runtime.h>
#include <math.h>

#define T_STEPS 168
#define INP     19
#define HID     64
#define ROWS    16
#define NTH     1024
#define HSTH    72    // h row stride (f16): 144 B, 16B-aligned
#define XSTH    40    // x row stride (f16): 80 B

typedef _Float16 half8   __attribute__((ext_vector_type(8)));
typedef float    floatx4 __attribute__((ext_vector_type(4)));
typedef float    floatx2 __attribute__((ext_vector_type(2)));

// 7-transcendental LSTM cell (r9-validated: absmax identical to 10-trans).
// g weights/bias carry tanh's x2; c kept 2x-scaled.
__device__ __forceinline__ float lstm_cell7(float zi, float zf, float zg2,
                                            float zo, float& c2) {
    zi  = fminf(fmaxf(zi,  -20.f), 20.f);
    zf  = fminf(fmaxf(zf,  -20.f), 20.f);
    zg2 = fminf(fmaxf(zg2, -40.f), 40.f);
    zo  = fminf(fmaxf(zo,  -20.f), 20.f);
    const float A = __expf(zi), F = __expf(zf), G = __expf(zg2), O = __expf(zo);
    const float pA = 1.f + A, pF = 1.f + F, pG = G + 1.f, mG = G - 1.f;
    const float d   = pA * pG;
    const float R   = __builtin_amdgcn_rcpf(d * pF);
    const float ft  = (F * d) * R;                  // sigmoid(zf)
    const float its = ((A * mG) * pF) * (R * 2.f);  // 2*sigmoid(zi)*tanh(zg)
    c2 = fmaf(ft, c2, its);
    c2 = fminf(fmaxf(c2, -35.f), 35.f);
    const float C2 = __expf(c2);
    const float R2 = __builtin_amdgcn_rcpf((1.f + O) * (C2 + 1.f));
    return (O * (C2 - 1.f)) * R2;                   // sigmoid(zo)*tanh(c)
}

// r8 shape (ROWS=16, grid=256, 1 block/CU) but 16 waves: each r8 wave-job is
// split in HALF along gates -> 4 waves/SIMD with zero duplicated work (r9
// lesson: ROWS=8 doubled per-CU work; this halves per-wave work instead).
//   wv = (lay<<3)|(uq<<1)|gp : lay=layer, uq=unit quarter, gp=gate pair
//   gp0 computes gates i,f; gp1 computes g,o (6-8 MFMAs, 32 w-regs each).
// Partner waves swap half their C-tiles via LDS (2 b64 wr + 2 b64 rd/lane),
// then each activates 2 of the 4 C-rows (7-trans cell). 2 barriers/iter.
__global__ __launch_bounds__(NTH) __attribute__((amdgpu_waves_per_eu(4, 4)))
void lstm2_mfma5_kernel(const float* __restrict__ x,
                        const float* __restrict__ Wih0, const float* __restrict__ Whh0,
                        const float* __restrict__ bih0, const float* __restrict__ bhh0,
                        const float* __restrict__ Wih1, const float* __restrict__ Whh1,
                        const float* __restrict__ bih1, const float* __restrict__ bhh1,
                        const float* __restrict__ Wfc,  const float* __restrict__ bfc,
                        float* __restrict__ out)
{
    __shared__ __align__(16) _Float16 xf [2][ROWS][XSTH];   // cols 19.. stay 0
    __shared__ __align__(16) _Float16 h1f[2][ROWS][HSTH];
    __shared__ __align__(16) _Float16 h2f[2][ROWS][HSTH];
    __shared__ float zx[2][4][4][4][16][2];   // [lay][uq][rg][quad][l16][2 gates]
    __shared__ float hout[ROWS][HID];         // fp32 h2(T-1) for FC

    const int tid  = threadIdx.x;
    const int b0   = blockIdx.x * ROWS;
    const int wv   = tid >> 6;
    const int lane = tid & 63;
    const int quad = lane >> 4;
    const int l16  = lane & 15;
    const int kq   = quad * 8;
    const int lay  = wv >> 3;          // 0: layer1(t), 1: layer2(t-1)
    const int uq   = (wv >> 1) & 3;    // unit quarter
    const int gp   = wv & 1;           // 0: gates i,f   1: gates g,o
    const int u    = uq * 16 + l16;    // my unit column

    // ---- B-fragments: 2 gates x 3-4 K-tiles (32 w-regs), loaded ONCE ----
    // B[k][n]: n=l16, k=kq+e. g-gate (gi==2) scaled x2 (tanh folding).
    half8 bfr[2][4];
    float bz[2];
#pragma unroll
    for (int gil = 0; gil < 2; ++gil) {
        const int gi = gp * 2 + gil;
        const int gr = gi * 64 + u;
        const float ws = (gi == 2) ? 2.f : 1.f;
        if (lay == 0) {
            const float* wr = Wih0 + gr * INP;
#pragma unroll
            for (int e = 0; e < 8; ++e) {
                const int k = kq + e;
                bfr[gil][0][e] = (k < INP) ? (_Float16)(ws * wr[k]) : (_Float16)0.0f;
            }
            const float* hr = Whh0 + gr * HID;
#pragma unroll
            for (int e = 0; e < 8; ++e) {
                bfr[gil][1][e] = (_Float16)(ws * hr[kq + e]);
                bfr[gil][2][e] = (_Float16)(ws * hr[32 + kq + e]);
            }
            bfr[gil][3] = bfr[gil][2];   // unused on this path
            bz[gil] = ws * (bih0[gr] + bhh0[gr]);
        } else {
            const float* ir = Wih1 + gr * HID;
            const float* hr = Whh1 + gr * HID;
#pragma unroll
            for (int e = 0; e < 8; ++e) {
                bfr[gil][0][e] = (_Float16)(ws * ir[kq + e]);
                bfr[gil][1][e] = (_Float16)(ws * ir[32 + kq + e]);
                bfr[gil][2][e] = (_Float16)(ws * hr[kq + e]);
                bfr[gil][3][e] = (_Float16)(ws * hr[32 + kq + e]);
            }
            bz[gil] = ws * (bih1[gr] + bhh1[gr]);
        }
    }

    // I activate C-rows rg = gp*2, gp*2+1  -> batch rows quad*4 + rg
    const int rg0 = gp * 2;       // my activation rg-pair
    const int wr0 = (1 - gp) * 2; // rg-pair I ship to my partner
    float cst[2] = {0.f, 0.f};    // 2x-scaled cell state for my 2 cells

    // ---- x staging constants (threads 0..303 stage one element/iter) ----
    int srr = 0, sii = 0;
    const float* xsrc = nullptr;
    if (tid < ROWS * INP) {
        srr = tid / INP; sii = tid - srr * INP;
        xsrc = x + ((size_t)(b0 + srr) * T_STEPS) * INP + sii;
    }

    // ---- init LDS ----
    for (int e = tid; e < 2 * ROWS * XSTH; e += NTH) ((_Float16*)xf)[e] = (_Float16)0.f;
    for (int e = tid; e < 2 * ROWS * HSTH; e += NTH) {
        ((_Float16*)h1f)[e] = (_Float16)0.f;
        ((_Float16*)h2f)[e] = (_Float16)0.f;
    }
    __syncthreads();
    float xregA = 0.f, xregB = 0.f;    // x(t+1), x(t+2) register pipeline
    if (xsrc) {
        xf[0][srr][sii] = (_Float16)xsrc[0];
        xregA = xsrc[INP];
        xregB = xsrc[2 * (size_t)INP];
    }
    __syncthreads();

    for (int t = 0; t <= T_STEPS; ++t) {
        // stage x(t+1) from reg (no vm wait); issue x(t+3) load early
        if (xsrc && (t + 1) < T_STEPS)
            xf[(t + 1) & 1][srr][sii] = (_Float16)xregA;
        float xnew = 0.f;
        if (xsrc) {
            const int tn = (t + 3 < T_STEPS) ? (t + 3) : (T_STEPS - 1);
            xnew = xsrc[(size_t)tn * INP];
        }

        const bool act = (lay == 0) ? (t < T_STEPS) : (t >= 1);
        floatx4 acc[2];
        if (act) {
#pragma unroll
            for (int gil = 0; gil < 2; ++gil)
                acc[gil] = (floatx4){bz[gil], bz[gil], bz[gil], bz[gil]};
            if (lay == 0) {
                const half8 ax = *(const half8*)&xf [t & 1][l16][kq];
                const half8 a0 = *(const half8*)&h1f[(t + 1) & 1][l16][kq];
                const half8 a1 = *(const half8*)&h1f[(t + 1) & 1][l16][32 + kq];
#pragma unroll
                for (int gil = 0; gil < 2; ++gil) {
                    acc[gil] = __builtin_amdgcn_mfma_f32_16x16x32_f16(ax, bfr[gil][0], acc[gil], 0, 0, 0);
                    acc[gil] = __builtin_amdgcn_mfma_f32_16x16x32_f16(a0, bfr[gil][1], acc[gil], 0, 0, 0);
                    acc[gil] = __builtin_amdgcn_mfma_f32_16x16x32_f16(a1, bfr[gil][2], acc[gil], 0, 0, 0);
                }
            } else {
                const half8 p0 = *(const half8*)&h1f[(t + 1) & 1][l16][kq];
                const half8 p1 = *(const half8*)&h1f[(t + 1) & 1][l16][32 + kq];
                const half8 q0 = *(const half8*)&h2f[t & 1][l16][kq];
                const half8 q1 = *(const half8*)&h2f[t & 1][l16][32 + kq];
#pragma unroll
                for (int gil = 0; gil < 2; ++gil) {
                    acc[gil] = __builtin_amdgcn_mfma_f32_16x16x32_f16(p0, bfr[gil][0], acc[gil], 0, 0, 0);
                    acc[gil] = __builtin_amdgcn_mfma_f32_16x16x32_f16(p1, bfr[gil][1], acc[gil], 0, 0, 0);
                    acc[gil] = __builtin_amdgcn_mfma_f32_16x16x32_f16(q0, bfr[gil][2], acc[gil], 0, 0, 0);
                    acc[gil] = __builtin_amdgcn_mfma_f32_16x16x32_f16(q1, bfr[gil][3], acc[gil], 0, 0, 0);
                }
            }
            // ship my 2 gates for the rg-pair my partner activates
#pragma unroll
            for (int j = 0; j < 2; ++j) {
                const int rg = wr0 + j;
                floatx2 v = {acc[0][rg], acc[1][rg]};
                *(floatx2*)&zx[lay][uq][rg][quad][l16][0] = v;
            }
        }
        __syncthreads();   // alpha: exchange halves + A-frag reads done

        if (act) {
#pragma unroll
            for (int j = 0; j < 2; ++j) {
                const int rg  = rg0 + j;
                const int row = quad * 4 + rg;
                const float o0 = acc[0][rg], o1 = acc[1][rg];
                const floatx2 p = *(const floatx2*)&zx[lay][uq][rg][quad][l16][0];
                const float zi  = gp ? p.x : o0;
                const float zf  = gp ? p.y : o1;
                const float zg2 = gp ? o0  : p.x;
                const float zo  = gp ? o1  : p.y;
                const float hv = lstm_cell7(zi, zf, zg2, zo, cst[j]);
                if (lay == 0) {
                    h1f[t & 1][row][u] = (_Float16)hv;              // h1(t)
                } else {
                    h2f[(t + 1) & 1][row][u] = (_Float16)hv;        // h2(t-1)
                    if (t == T_STEPS) hout[row][u] = hv;            // fp32 for FC
                }
            }
        }
        xregA = xregB; xregB = xnew;
        __syncthreads();   // beta: h/x updates visible to next iter
    }

    // ---- FC epilogue: out[b] = h2(T-1)[b,:] . Wfc + bfc ----
    if (tid < ROWS) {
        float a = bfc[0];
        const float* hr = hout[tid];
#pragma unroll
        for (int k = 0; k < HID; ++k)
            a = fmaf(hr[k], Wfc[k], a);
        out[b0 + tid] = a;
    }
}

extern "C" void kernel_launch(void* const* d_in, const int* in_sizes, int n_in,
                              void* d_out, int out_size, void* d_ws, size_t ws_size,
                              hipStream_t stream) {
    const float* x    = (const float*)d_in[0];
    const float* Wih0 = (const float*)d_in[1];
    const float* Whh0 = (const float*)d_in[2];
    const float* bih0 = (const float*)d_in[3];
    const float* bhh0 = (const float*)d_in[4];
    const float* Wih1 = (const float*)d_in[5];
    const float* Whh1 = (const float*)d_in[6];
    const float* bih1 = (const float*)d_in[7];
    const float* bhh1 = (const float*)d_in[8];
    const float* Wfc  = (const float*)d_in[9];
    const float* bfc  = (const float*)d_in[10];
    float* out = (float*)d_out;

    const int B = in_sizes[0] / (T_STEPS * INP);   // 4096
    const int grid = B / ROWS;                     // 256 workgroups, 1 per CU

    lstm2_mfma5_kernel<<<dim3(grid), dim3(NTH), 0, stream>>>(
        x, Wih0, Whh0, bih0, bhh0, Wih1, Whh1, bih1, bhh1, Wfc, bfc, out);
}

// Round 11
// 257.263 us; speedup vs baseline: 1.2575x; 1.2575x over previous
//
#include <hip/hip_runtime.h>
#include <math.h>

#define T_STEPS 168
#define INP     19
#define HID     64
#define ROWS    16
#define NTH     512
#define HSTH    72    // h row stride (f16): 144 B, 16B-aligned
#define XSTH    40    // x row stride (f16): 80 B

typedef _Float16 half8   __attribute__((ext_vector_type(8)));
typedef float    floatx4 __attribute__((ext_vector_type(4)));

__device__ __forceinline__ float fast_sigmoid(float x) {
    return __builtin_amdgcn_rcpf(1.0f + __expf(-x));
}
__device__ __forceinline__ float fast_tanh(float x) {
    return 1.0f - 2.0f * __builtin_amdgcn_rcpf(1.0f + __expf(2.0f * x));
}

// LDS-visibility-only barrier: s_waitcnt lgkmcnt(0) + s_barrier, WITHOUT the
// vmcnt(0) drain __syncthreads() emits. The x-prefetch global load issued
// each iter is consumed 2 iters later (thread-local register) -- forcing it
// to complete at every barrier (r8) serialized its L3/HBM latency into the
// iteration wall. LDS h/x handoff only needs lgkmcnt.
#define LDS_BARRIER() asm volatile("s_waitcnt lgkmcnt(0)\n\ts_barrier" ::: "memory")

// r8 structure exactly (best measured: 186 us dispatch): ROWS=16, grid=256,
// 8 waves (4 layer1(t) + 4 layer2(t-1) skew), per-wave all-4-gates MFMA,
// activations in C-layout, c-state in regs, double-buffered xf/h1f/h2f,
// single barrier/iter. r9 (ROWS=8) and r10 (gate-split) both proved that
// buying 4 waves/SIMD costs >=40% extra issue work -- net regressions.
// This round: LDS_BARRIER replaces __syncthreads in the loop + depth-2 x pipe.
__global__ __launch_bounds__(NTH) __attribute__((amdgpu_waves_per_eu(2, 2)))
void lstm2_mfma6_kernel(const float* __restrict__ x,
                        const float* __restrict__ Wih0, const float* __restrict__ Whh0,
                        const float* __restrict__ bih0, const float* __restrict__ bhh0,
                        const float* __restrict__ Wih1, const float* __restrict__ Whh1,
                        const float* __restrict__ bih1, const float* __restrict__ bhh1,
                        const float* __restrict__ Wfc,  const float* __restrict__ bfc,
                        float* __restrict__ out)
{
    __shared__ __align__(16) _Float16 xf [2][ROWS][XSTH];   // cols 19.. stay 0
    __shared__ __align__(16) _Float16 h1f[2][ROWS][HSTH];
    __shared__ __align__(16) _Float16 h2f[2][ROWS][HSTH];
    __shared__ float hout[ROWS][HID];                       // fp32 h2(T-1) for FC

    const int tid  = threadIdx.x;
    const int b0   = blockIdx.x * ROWS;
    const int wv   = tid >> 6;
    const int lane = tid & 63;
    const int quad = lane >> 4;
    const int l16  = lane & 15;
    const int kq   = quad * 8;         // k-offset inside a 32-wide K-tile
    const int lay  = wv >> 2;          // 0: layer1(t), 1: layer2(t-1)
    const int uq   = wv & 3;           // unit quarter
    const int u    = uq * 16 + l16;    // my unit column

    // ---- B-fragments (weights, f16) + bias: loaded ONCE ----
    // B[k][n]: n = lane&15, k = quad*8 + e
    half8 bfr[4][4];
    float bz[4];
#pragma unroll
    for (int gi = 0; gi < 4; ++gi) {
        const int gr = gi * 64 + u;
        if (lay == 0) {
            const float* wr = Wih0 + gr * INP;
#pragma unroll
            for (int e = 0; e < 8; ++e) {
                const int k = kq + e;
                bfr[gi][0][e] = (k < INP) ? (_Float16)wr[k] : (_Float16)0.0f;
            }
            const float* hr = Whh0 + gr * HID;
#pragma unroll
            for (int e = 0; e < 8; ++e) {
                bfr[gi][1][e] = (_Float16)hr[kq + e];
                bfr[gi][2][e] = (_Float16)hr[32 + kq + e];
            }
            bfr[gi][3] = bfr[gi][2];   // unused on this path
            bz[gi] = bih0[gr] + bhh0[gr];
        } else {
            const float* ir = Wih1 + gr * HID;
            const float* hr = Whh1 + gr * HID;
#pragma unroll
            for (int e = 0; e < 8; ++e) {
                bfr[gi][0][e] = (_Float16)ir[kq + e];
                bfr[gi][1][e] = (_Float16)ir[32 + kq + e];
                bfr[gi][2][e] = (_Float16)hr[kq + e];
                bfr[gi][3][e] = (_Float16)hr[32 + kq + e];
            }
            bz[gi] = bih1[gr] + bhh1[gr];
        }
    }

    // cell state: rows quad*4..+3 of unit u
    float cst[4] = {0.f, 0.f, 0.f, 0.f};

    // ---- x staging constants (threads 0..303 stage one element/iter) ----
    int srr = 0, sii = 0;
    const float* xsrc = nullptr;
    if (tid < ROWS * INP) {
        srr = tid / INP; sii = tid - srr * INP;
        xsrc = x + ((size_t)(b0 + srr) * T_STEPS) * INP + sii;
    }

    // ---- init LDS (both buffers zero; pad cols stay zero forever) ----
    for (int e = tid; e < 2 * ROWS * XSTH; e += NTH) ((_Float16*)xf)[e] = (_Float16)0.f;
    for (int e = tid; e < 2 * ROWS * HSTH; e += NTH) {
        ((_Float16*)h1f)[e] = (_Float16)0.f;
        ((_Float16*)h2f)[e] = (_Float16)0.f;
    }
    __syncthreads();
    float xregA = 0.f, xregB = 0.f;    // x(t+1), x(t+2) register pipeline
    if (xsrc) {
        xf[0][srr][sii] = (_Float16)xsrc[0];   // stage x(0) directly
        xregA = xsrc[INP];                     // x(1)
        xregB = xsrc[2 * (size_t)INP];         // x(2)
    }
    __syncthreads();

    for (int t = 0; t <= T_STEPS; ++t) {
        // ---- stage x(t+1) from reg (loaded 2 iters ago); issue x(t+3) ----
        if (xsrc && (t + 1) < T_STEPS)
            xf[(t + 1) & 1][srr][sii] = (_Float16)xregA;
        float xnew = 0.f;
        if (xsrc) {
            const int tn = (t + 3 < T_STEPS) ? (t + 3) : (T_STEPS - 1);
            xnew = xsrc[(size_t)tn * INP];
        }

        const bool act = (lay == 0) ? (t < T_STEPS) : (t >= 1);
        if (act) {
            floatx4 acc[4];
#pragma unroll
            for (int gi = 0; gi < 4; ++gi)
                acc[gi] = (floatx4){bz[gi], bz[gi], bz[gi], bz[gi]};
            if (lay == 0) {
                // A[m=lane&15][k=quad*8+e]
                const half8 ax = *(const half8*)&xf [t & 1][l16][kq];
                const half8 a0 = *(const half8*)&h1f[(t + 1) & 1][l16][kq];
                const half8 a1 = *(const half8*)&h1f[(t + 1) & 1][l16][32 + kq];
#pragma unroll
                for (int gi = 0; gi < 4; ++gi) {
                    acc[gi] = __builtin_amdgcn_mfma_f32_16x16x32_f16(ax, bfr[gi][0], acc[gi], 0, 0, 0);
                    acc[gi] = __builtin_amdgcn_mfma_f32_16x16x32_f16(a0, bfr[gi][1], acc[gi], 0, 0, 0);
                    acc[gi] = __builtin_amdgcn_mfma_f32_16x16x32_f16(a1, bfr[gi][2], acc[gi], 0, 0, 0);
                }
            } else {
                const half8 p0 = *(const half8*)&h1f[(t + 1) & 1][l16][kq];
                const half8 p1 = *(const half8*)&h1f[(t + 1) & 1][l16][32 + kq];
                const half8 q0 = *(const half8*)&h2f[t & 1][l16][kq];
                const half8 q1 = *(const half8*)&h2f[t & 1][l16][32 + kq];
#pragma unroll
                for (int gi = 0; gi < 4; ++gi) {
                    acc[gi] = __builtin_amdgcn_mfma_f32_16x16x32_f16(p0, bfr[gi][0], acc[gi], 0, 0, 0);
                    acc[gi] = __builtin_amdgcn_mfma_f32_16x16x32_f16(p1, bfr[gi][1], acc[gi], 0, 0, 0);
                    acc[gi] = __builtin_amdgcn_mfma_f32_16x16x32_f16(q0, bfr[gi][2], acc[gi], 0, 0, 0);
                    acc[gi] = __builtin_amdgcn_mfma_f32_16x16x32_f16(q1, bfr[gi][3], acc[gi], 0, 0, 0);
                }
            }
            // activations in C-layout: lane owns cells (row=quad*4+rg, u)
#pragma unroll
            for (int rg = 0; rg < 4; ++rg) {
                const float ig = fast_sigmoid(acc[0][rg]);
                const float fg = fast_sigmoid(acc[1][rg]);
                const float gg = fast_tanh(acc[2][rg]);
                const float og = fast_sigmoid(acc[3][rg]);
                cst[rg] = fg * cst[rg] + ig * gg;
                const float hv = og * fast_tanh(cst[rg]);
                const int row = quad * 4 + rg;
                if (lay == 0) {
                    h1f[t & 1][row][u] = (_Float16)hv;              // h1(t)
                } else {
                    h2f[(t + 1) & 1][row][u] = (_Float16)hv;        // h2(t-1)
                    if (t == T_STEPS) hout[row][u] = hv;            // fp32 for FC
                }
            }
        }
        xregA = xregB; xregB = xnew;
        LDS_BARRIER();   // lgkmcnt-only: h/x LDS handoff visible; x global
                         // prefetch stays in flight across the barrier
    }
    __syncthreads();     // full barrier once before epilogue

    // ---- FC epilogue: out[b] = h2(T-1)[b,:] . Wfc + bfc ----
    if (tid < ROWS) {
        float a = bfc[0];
        const float* hr = hout[tid];
#pragma unroll
        for (int k = 0; k < HID; ++k)
            a = fmaf(hr[k], Wfc[k], a);
        out[b0 + tid] = a;
    }
}

extern "C" void kernel_launch(void* const* d_in, const int* in_sizes, int n_in,
                              void* d_out, int out_size, void* d_ws, size_t ws_size,
                              hipStream_t stream) {
    const float* x    = (const float*)d_in[0];
    const float* Wih0 = (const float*)d_in[1];
    const float* Whh0 = (const float*)d_in[2];
    const float* bih0 = (const float*)d_in[3];
    const float* bhh0 = (const float*)d_in[4];
    const float* Wih1 = (const float*)d_in[5];
    const float* Whh1 = (const float*)d_in[6];
    const float* bih1 = (const float*)d_in[7];
    const float* bhh1 = (const float*)d_in[8];
    const float* Wfc  = (const float*)d_in[9];
    const float* bfc  = (const float*)d_in[10];
    float* out = (float*)d_out;

    const int B = in_sizes[0] / (T_STEPS * INP);   // 4096
    const int grid = B / ROWS;                     // 256 workgroups, 1 per CU

    lstm2_mfma6_kernel<<<dim3(grid), dim3(NTH), 0, stream>>>(
        x, Wih0, Whh0, bih0, bhh0, Wih1, Whh1, bih1, bhh1, Wfc, bfc, out);
}